// Round 6
// baseline (1011.342 us; speedup 1.0000x reference)
//
#include <hip/hip_runtime.h>
#include <stdint.h>

#define NN 100000
#define NE 1600000
#define NE4 (NE / 4)
#define NNP1 100008          // rowptr row stride, padded for int4 alignment
#define NBK 196              // node buckets of 512 (100000 -> 196)
#define NSL 64               // edge slices (blocks) per relation for build

typedef __attribute__((ext_vector_type(8))) short bfrag;   // 8 bf16 = 4 VGPRs
typedef __attribute__((ext_vector_type(4))) float ffrag;   // mfma accumulator

__device__ __forceinline__ uint16_t f2bf(float f) {
  uint32_t u = __float_as_uint(f);
  u += 0x7fff + ((u >> 16) & 1);   // round-to-nearest-even
  return (uint16_t)(u >> 16);
}
__device__ __forceinline__ uint32_t pack2(float a, float b) {
  return (uint32_t)f2bf(a) | ((uint32_t)f2bf(b) << 16);
}

// ---------- x (fp32) -> h (bf16, packed pairs) ----------
__global__ void k_cast_x(const float* __restrict__ x, uint32_t* __restrict__ h) {
  int n = NN * 64;
  for (int i = blockIdx.x * blockDim.x + threadIdx.x; i < n; i += gridDim.x * blockDim.x) {
    float2 v = ((const float2*)x)[i];
    h[i] = pack2(v.x, v.y);
  }
}

// ---------- Wc[l][r] = Wg[l][r] @ Wfc[l]  (fp32, folds both matmuls into one) ----------
__global__ void k_matmul_wc(const float* __restrict__ Wg0, const float* __restrict__ Wg1,
                            const float* __restrict__ Wfc, float* __restrict__ Wc) {
  int b = blockIdx.x;                 // 24 blocks: m*4 + kq
  int m = b >> 2, kq = b & 3;
  int l = m / 3, rel = m % 3;
  int t = threadIdx.x;
  int n = t & 127, kh = t >> 7;
  int k0 = kq * 32 + kh * 16;
  const float* Wg = (l ? Wg1 : Wg0) + rel * 16384;
  const float* Wf = Wfc + (size_t)l * 16384;
  for (int k = k0; k < k0 + 16; k++) {
    float acc = 0.f;
    for (int kk = 0; kk < 128; kk++) acc = fmaf(Wg[k * 128 + kk], Wf[kk * 128 + n], acc);
    Wc[(size_t)m * 16384 + k * 128 + n] = acc;
  }
}

// ---------- pre-swizzle the 6 Wc matrices into MFMA B-fragment order ----------
// wswz[m][f=t*8+ct][lane][j] = Wc[m][t*32 + (lane>>4)*8 + j][ct*16 + (lane&15)]
__global__ void k_prep_w(const float* __restrict__ Wc, uint16_t* __restrict__ wswz) {
  int idx = blockIdx.x * 256 + threadIdx.x;          // 0 .. 98303 (6 * 16384)
  int rem = idx & 16383;
  int m = idx >> 14;
  int j = rem & 7;
  int lane = (rem >> 3) & 63;
  int f = rem >> 9;                                   // t*8+ct
  int t = f >> 3, ct = f & 7;
  int k = t * 32 + (lane >> 4) * 8 + j;
  int n = ct * 16 + (lane & 15);
  wswz[idx] = f2bf(Wc[(size_t)m * 16384 + k * 128 + n]);
}

// ---------- tiny constants: bias2 = (sum_r bg)@Wfc + bfc ; BN folded to g2,b2 ----------
__global__ void k_prep_consts(const float* __restrict__ bg0, const float* __restrict__ bg1,
                              const float* __restrict__ Wfc, const float* __restrict__ bfc,
                              const float* __restrict__ gamma, const float* __restrict__ beta,
                              const float* __restrict__ mean, const float* __restrict__ var,
                              float* __restrict__ cst) {
  int tid = threadIdx.x;              // 0..255 = l*128 + n
  int l = tid >> 7, n = tid & 127;
  const float* bg = l ? bg1 : bg0;
  float acc = bfc[l * 128 + n];
  for (int k = 0; k < 128; k++) {
    float bsum = bg[k] + bg[128 + k] + bg[256 + k];
    acc += bsum * Wfc[l * 16384 + k * 128 + n];
  }
  cst[tid] = acc;                                    // bias2
  float g = gamma[tid] * rsqrtf(var[tid] + 1e-5f);
  cst[256 + tid] = g;                                // g2
  cst[512 + tid] = beta[tid] - mean[tid] * g;        // b2
}

// ---------- build 1: per-slice LDS bucket histograms, tiny global merge ----------
__global__ void k_bhist(const int* __restrict__ s0, const int* __restrict__ s1,
                        const int* __restrict__ s2, const int* __restrict__ d0,
                        const int* __restrict__ d1, const int* __restrict__ d2,
                        uint32_t* __restrict__ bh) {
  int r = blockIdx.y, blk = blockIdx.x, t = threadIdx.x;
  __shared__ uint32_t hD[NBK], hS[NBK];
  for (int i = t; i < NBK; i += 256) { hD[i] = 0; hS[i] = 0; }
  __syncthreads();
  const int4* sp = (const int4*)((r == 0) ? s0 : (r == 1) ? s1 : s2);
  const int4* dp = (const int4*)((r == 0) ? d0 : (r == 1) ? d1 : d2);
  int base = blk * (NE4 / NSL);
  for (int i = t; i < NE4 / NSL; i += 256) {
    int4 s = sp[base + i];
    int4 d = dp[base + i];
    atomicAdd(&hD[d.x >> 9], 1u); atomicAdd(&hD[d.y >> 9], 1u);
    atomicAdd(&hD[d.z >> 9], 1u); atomicAdd(&hD[d.w >> 9], 1u);
    atomicAdd(&hS[s.x >> 9], 1u); atomicAdd(&hS[s.y >> 9], 1u);
    atomicAdd(&hS[s.z >> 9], 1u); atomicAdd(&hS[s.w >> 9], 1u);
  }
  __syncthreads();
  for (int i = t; i < NBK; i += 256) {
    if (hD[i]) atomicAdd(&bh[r * NBK + i], hD[i]);
    if (hS[i]) atomicAdd(&bh[(3 + r) * NBK + i], hS[i]);
  }
}

// ---------- build 2: exclusive scan of each segment's 196 bucket counts ----------
__global__ void k_bscan(const uint32_t* __restrict__ bh, int* __restrict__ bases,
                        uint32_t* __restrict__ cur, int* __restrict__ rowptr) {
  int seg = blockIdx.x, t = threadIdx.x;     // 256 threads
  int lane = t & 63, wid = t >> 6;
  int v = (t < NBK) ? (int)bh[seg * NBK + t] : 0;
  int x = v;
#pragma unroll
  for (int o = 1; o < 64; o <<= 1) { int y = __shfl_up(x, o); if (lane >= o) x += y; }
  __shared__ int ws[4];
  if (lane == 63) ws[wid] = x;
  __syncthreads();
  int woff = 0;
  for (int i = 0; i < wid; i++) woff += ws[i];
  int incl = woff + x, excl = incl - v;
  if (t < NBK) { bases[seg * (NBK + 1) + t] = excl; cur[seg * NBK + t] = (uint32_t)excl; }
  if (t == 255) bases[seg * (NBK + 1) + NBK] = incl;   // = NE
  if (seg < 3 && t == 0) rowptr[seg * NNP1 + NN] = NE;
}

// ---------- build 3: scatter edges into buckets (block-chunk claims, LDS cursors) ----------
__global__ void k_bscatter(const int* __restrict__ s0, const int* __restrict__ s1,
                           const int* __restrict__ s2, const int* __restrict__ d0,
                           const int* __restrict__ d1, const int* __restrict__ d2,
                           uint32_t* __restrict__ cur, uint32_t* __restrict__ pairs,
                           uint16_t* __restrict__ srcs) {
  int r = blockIdx.y, blk = blockIdx.x, t = threadIdx.x;
  __shared__ uint32_t hD[NBK], hS[NBK];
  for (int i = t; i < NBK; i += 256) { hD[i] = 0; hS[i] = 0; }
  __syncthreads();
  const int4* sp = (const int4*)((r == 0) ? s0 : (r == 1) ? s1 : s2);
  const int4* dp = (const int4*)((r == 0) ? d0 : (r == 1) ? d1 : d2);
  int base = blk * (NE4 / NSL);
  for (int i = t; i < NE4 / NSL; i += 256) {
    int4 s = sp[base + i];
    int4 d = dp[base + i];
    atomicAdd(&hD[d.x >> 9], 1u); atomicAdd(&hD[d.y >> 9], 1u);
    atomicAdd(&hD[d.z >> 9], 1u); atomicAdd(&hD[d.w >> 9], 1u);
    atomicAdd(&hS[s.x >> 9], 1u); atomicAdd(&hS[s.y >> 9], 1u);
    atomicAdd(&hS[s.z >> 9], 1u); atomicAdd(&hS[s.w >> 9], 1u);
  }
  __syncthreads();
  for (int i = t; i < NBK; i += 256) {
    hD[i] = atomicAdd(&cur[r * NBK + i], hD[i]);
    hS[i] = atomicAdd(&cur[(3 + r) * NBK + i], hS[i]);
  }
  __syncthreads();
  uint32_t* pr = pairs + (size_t)r * NE;
  uint16_t* sr = srcs + (size_t)r * NE;
#define SCAT1(S, D) { \
    uint32_t p = atomicAdd(&hD[(D) >> 9], 1u); \
    pr[p] = (uint32_t)(((D) & 511) << 17) | (uint32_t)(S); \
    uint32_t q = atomicAdd(&hS[(S) >> 9], 1u); \
    sr[q] = (uint16_t)((S) & 511); }
  for (int i = t; i < NE4 / NSL; i += 256) {
    int4 s = sp[base + i];
    int4 d = dp[base + i];
    SCAT1(s.x, d.x) SCAT1(s.y, d.y) SCAT1(s.z, d.z) SCAT1(s.w, d.w)
  }
#undef SCAT1
}

// ---------- build 4: per-bucket out-degree -> s_out (must run BEFORE bucket_csr) ----------
__global__ void k_bucket_sout(const uint16_t* __restrict__ srcs, const int* __restrict__ bases,
                              float* __restrict__ s_out) {
  int b = blockIdx.x, r = blockIdx.y, t = threadIdx.x;
  int node0 = b << 9;
  int nc = min(512, NN - node0);
  int rb = bases[(3 + r) * (NBK + 1) + b];
  int m = bases[(3 + r) * (NBK + 1) + b + 1] - rb;
  __shared__ int cnt[512];
  cnt[t] = 0; cnt[t + 256] = 0;
  __syncthreads();
  const uint16_t* pp = srcs + (size_t)r * NE + rb;
  for (int i = t; i < m; i += 256) atomicAdd(&cnt[pp[i]], 1);
  __syncthreads();
  for (int i = t; i < nc; i += 256)
    s_out[r * NN + node0 + i] = rsqrtf((float)(cnt[i] < 1 ? 1 : cnt[i]));
}

// ---------- build 5: per-bucket CSR (rowptr, s_in, col2 = (src, s_out[src])) ----------
__global__ void k_bucket_csr(const uint32_t* __restrict__ pairs, const int* __restrict__ bases,
                             const float* __restrict__ s_out, int* __restrict__ rowptr,
                             float* __restrict__ s_in, int2* __restrict__ col2) {
  int b = blockIdx.x, r = blockIdx.y, t = threadIdx.x;
  int node0 = b << 9;
  int nc = min(512, NN - node0);
  int rb = bases[r * (NBK + 1) + b];
  int m = bases[r * (NBK + 1) + b + 1] - rb;
  __shared__ int cnt[512];
  __shared__ int exc[512];
  __shared__ int ws[4];
  cnt[t] = 0; cnt[t + 256] = 0;
  __syncthreads();
  const uint32_t* pp = pairs + (size_t)r * NE + rb;
  for (int i = t; i < m; i += 256) atomicAdd(&cnt[pp[i] >> 17], 1);
  __syncthreads();
  int v0 = cnt[2 * t], v1 = cnt[2 * t + 1];
  int s = v0 + v1, x = s;
  int lane = t & 63, wid = t >> 6;
#pragma unroll
  for (int o = 1; o < 64; o <<= 1) { int y = __shfl_up(x, o); if (lane >= o) x += y; }
  if (lane == 63) ws[wid] = x;
  __syncthreads();
  int woff = 0;
  for (int i = 0; i < wid; i++) woff += ws[i];
  int e0 = woff + x - s;
  exc[2 * t] = e0;
  exc[2 * t + 1] = e0 + v0;
  __syncthreads();
  for (int i = t; i < nc; i += 256) {
    rowptr[r * NNP1 + node0 + i] = rb + exc[i];
    s_in[r * NN + node0 + i] = rsqrtf((float)(cnt[i] < 1 ? 1 : cnt[i]));
  }
  __syncthreads();
  int2* cl = col2 + (size_t)r * NE + rb;
  for (int i = t; i < m; i += 256) {
    uint32_t e = pp[i];
    int src = (int)(e & 0x1FFFF);
    int p = atomicAdd(&exc[e >> 17], 1);
    cl[p] = make_int2(src, __float_as_int(s_out[r * NN + src]));
  }
}

// ---------- aggregation: agg_r[n] = rsqrt(deg_in) * sum_e w_e * h[src_e] ----------
// one wave per dst node; lane covers feature pair (2*lane, 2*lane+1).
// node forced wave-uniform via readfirstlane so edge (src,w) reads become
// SCALAR loads (SGPR) -> no readlane, no per-edge VALU beyond unpack+fma.
__global__ void k_aggregate(const uint32_t* __restrict__ h, const int* __restrict__ rowptr,
                            const int2* __restrict__ col2, const float* __restrict__ s_in,
                            uint32_t* __restrict__ agg) {
  int r = blockIdx.y;
  int node = __builtin_amdgcn_readfirstlane(blockIdx.x * 4 + (threadIdx.x >> 6));
  int lane = threadIdx.x & 63;
  const int* rp = rowptr + r * NNP1;
  int beg = rp[node], end = rp[node + 1];
  const int2* cl = col2 + (size_t)r * NE;
  float a0 = 0.f, a1 = 0.f;
  int j = beg;
  for (; j + 8 <= end; j += 8) {
    uint32_t hv[8]; float ww[8];
#pragma unroll
    for (int u = 0; u < 8; u++) {
      int2 e = cl[j + u];                       // uniform addr -> s_load
      ww[u] = __int_as_float(e.y);
      hv[u] = h[(size_t)e.x * 64 + lane];       // SGPR base + lane*4
    }
#pragma unroll
    for (int u = 0; u < 8; u++) {
      a0 = fmaf(__uint_as_float(hv[u] << 16), ww[u], a0);
      a1 = fmaf(__uint_as_float(hv[u] & 0xffff0000u), ww[u], a1);
    }
  }
  for (; j < end; j++) {
    int2 e = cl[j];
    uint32_t hv = h[(size_t)e.x * 64 + lane];
    float w = __int_as_float(e.y);
    a0 = fmaf(__uint_as_float(hv << 16), w, a0);
    a1 = fmaf(__uint_as_float(hv & 0xffff0000u), w, a1);
  }
  float sc = s_in[r * NN + node];
  agg[((size_t)r * NN + node) * 64 + lane] = pack2(a0 * sc, a1 * sc);
}

// ---------- fused FC: out = relu([agg0|agg1|agg2] @ [Wc0;Wc1;Wc2] + bias2); BN folded ----------
// 64-row tiles per wave (12 loads : 32 MFMA per kt), K=384, B frags from L1/L2.
__global__ __launch_bounds__(256, 2) void k_fc2(const uint32_t* __restrict__ agg,
                                                const short* __restrict__ wswz,
                                                const float* __restrict__ cst, int l,
                                                uint16_t* __restrict__ hout,
                                                float* __restrict__ fout, int wf32) {
  int lane = threadIdx.x & 63;
  int wid = threadIdx.x >> 6;
  int q = lane >> 4, n0 = lane & 15;
  const bfrag* wb = (const bfrag*)(wswz + (size_t)(l * 3) * 16384);  // 3 matrices
  float bb[8], gg[8], b2v[8];
#pragma unroll
  for (int ct = 0; ct < 8; ct++) {
    int c = l * 128 + ct * 16 + n0;
    bb[ct] = cst[c];
    gg[ct] = cst[256 + c];
    b2v[ct] = cst[512 + c];
  }
  const int ntiles = (NN + 63) / 64;   // 1563 (last tile partial: 32 rows)
  for (int tile = blockIdx.x * 4 + wid; tile < ntiles; tile += gridDim.x * 4) {
    ffrag acc[4][8];
#pragma unroll
    for (int s = 0; s < 4; s++)
#pragma unroll
      for (int ct = 0; ct < 8; ct++) acc[s][ct] = (ffrag){0.f, 0.f, 0.f, 0.f};
    for (int kt = 0; kt < 12; kt++) {          // K=384 in steps of 32
      int rel = kt >> 2, kt4 = kt & 3;
      const uint32_t* A = agg + (size_t)rel * NN * 64 + kt4 * 16 + q * 4;
      bfrag a[4];
#pragma unroll
      for (int s = 0; s < 4; s++) {
        int row = tile * 64 + s * 16 + n0;
        row = row < NN ? row : 0;
        a[s] = *(const bfrag*)(A + (size_t)row * 64);
      }
      const bfrag* wk = wb + (size_t)rel * 2048 + (kt4 * 8) * 64 + lane;
#pragma unroll
      for (int ct = 0; ct < 8; ct++) {
        bfrag B = wk[ct * 64];
#pragma unroll
        for (int s = 0; s < 4; s++)
          acc[s][ct] = __builtin_amdgcn_mfma_f32_16x16x32_bf16(a[s], B, acc[s][ct], 0, 0, 0);
      }
    }
#pragma unroll
    for (int s = 0; s < 4; s++) {
      int orow = tile * 64 + s * 16 + q * 4;
#pragma unroll
      for (int ct = 0; ct < 8; ct++) {
#pragma unroll
        for (int i = 0; i < 4; i++) {
          if (orow + i < NN) {
            float y = acc[s][ct][i] + bb[ct];
            y = fmaxf(y, 0.f);
            float hv = fmaf(y, gg[ct], b2v[ct]);
            size_t oi = (size_t)(orow + i) * 128 + ct * 16 + n0;
            if (wf32) fout[oi] = hv;
            else hout[oi] = f2bf(hv);
          }
        }
      }
    }
  }
}

extern "C" void kernel_launch(void* const* d_in, const int* in_sizes, int n_in,
                              void* d_out, int out_size, void* d_ws, size_t ws_size,
                              hipStream_t stream) {
  const float* x = (const float*)d_in[0];
  const int* s0 = (const int*)d_in[1]; const int* d0 = (const int*)d_in[2];
  const int* s1 = (const int*)d_in[3]; const int* d1 = (const int*)d_in[4];
  const int* s2 = (const int*)d_in[5]; const int* d2 = (const int*)d_in[6];
  const float* Wg0 = (const float*)d_in[7];
  const float* bg0 = (const float*)d_in[8];
  const float* Wg1 = (const float*)d_in[9];
  const float* bg1 = (const float*)d_in[10];
  const float* Wfc = (const float*)d_in[11];
  const float* bfc = (const float*)d_in[12];
  const float* gamma = (const float*)d_in[13];
  const float* beta = (const float*)d_in[14];
  const float* mean = (const float*)d_in[15];
  const float* var = (const float*)d_in[16];

  char* ws = (char*)d_ws;
  size_t off = 0;
  auto alloc = [&](size_t bytes) { size_t o = off; off = (off + bytes + 255) & ~(size_t)255; return o; };
  size_t o_bh    = alloc((size_t)6 * NBK * 4);
  size_t o_bases = alloc((size_t)6 * (NBK + 1) * 4);
  size_t o_cur   = alloc((size_t)6 * NBK * 4);
  size_t o_sin   = alloc((size_t)3 * NN * 4);
  size_t o_sout  = alloc((size_t)3 * NN * 4);
  size_t o_rp    = alloc((size_t)3 * NNP1 * 4);
  size_t o_col2  = alloc((size_t)3 * NE * 8);
  size_t o_wc    = alloc((size_t)6 * 16384 * 4);
  size_t o_wswz  = alloc((size_t)6 * 16384 * 2);
  size_t o_cst   = alloc((size_t)768 * 4);
  size_t o_h     = alloc((size_t)NN * 128 * 2);
  size_t o_agg   = alloc((size_t)3 * NN * 128 * 2);
  (void)ws_size; (void)in_sizes; (void)n_in; (void)out_size;

  uint32_t* bh   = (uint32_t*)(ws + o_bh);
  int* bases     = (int*)(ws + o_bases);
  uint32_t* cur  = (uint32_t*)(ws + o_cur);
  float* s_in    = (float*)(ws + o_sin);
  float* s_out   = (float*)(ws + o_sout);
  int* rowptr    = (int*)(ws + o_rp);
  int2* col2     = (int2*)(ws + o_col2);
  float* Wc      = (float*)(ws + o_wc);
  uint16_t* wswz = (uint16_t*)(ws + o_wswz);
  float* cst     = (float*)(ws + o_cst);
  uint32_t* h    = (uint32_t*)(ws + o_h);
  uint32_t* agg  = (uint32_t*)(ws + o_agg);
  // pairs/srcs are dead after build; alias them into the agg region (28.8 MB < 76.8 MB)
  uint32_t* pairs = (uint32_t*)(ws + o_agg);
  uint16_t* srcs  = (uint16_t*)(ws + o_agg + (size_t)3 * NE * 4);

  hipMemsetAsync(ws + o_bh, 0, (size_t)6 * NBK * 4, stream);

  k_cast_x<<<2048, 256, 0, stream>>>(x, h);
  k_matmul_wc<<<24, 256, 0, stream>>>(Wg0, Wg1, Wfc, Wc);
  k_prep_w<<<384, 256, 0, stream>>>(Wc, wswz);
  k_prep_consts<<<1, 256, 0, stream>>>(bg0, bg1, Wfc, bfc, gamma, beta, mean, var, cst);
  k_bhist<<<dim3(NSL, 3), 256, 0, stream>>>(s0, s1, s2, d0, d1, d2, bh);
  k_bscan<<<6, 256, 0, stream>>>(bh, bases, cur, rowptr);
  k_bscatter<<<dim3(NSL, 3), 256, 0, stream>>>(s0, s1, s2, d0, d1, d2, cur, pairs, srcs);
  k_bucket_sout<<<dim3(NBK, 3), 256, 0, stream>>>(srcs, bases, s_out);
  k_bucket_csr<<<dim3(NBK, 3), 256, 0, stream>>>(pairs, bases, s_out, rowptr, s_in, col2);

  for (int l = 0; l < 2; l++) {
    k_aggregate<<<dim3(25000, 3), 256, 0, stream>>>(h, rowptr, col2, s_in, agg);
    k_fc2<<<391, 256, 0, stream>>>(agg, (const short*)wswz, cst, l,
                                   (uint16_t*)h, (float*)d_out, l);
  }
}

// Round 7
// 768.067 us; speedup vs baseline: 1.3167x; 1.3167x over previous
//
#include <hip/hip_runtime.h>
#include <stdint.h>

#define NN 100000
#define NE 1600000
#define NE4 (NE / 4)
#define NNP1 100008          // rowptr row stride, padded for int4 alignment
#define NBK 196              // node buckets of 512 (100000 -> 196)
#define NSL 64               // edge slices (blocks) per relation for build
#define APAD 196             // LDS A row stride in u32 (196%32==4 -> 2-way free)

typedef __attribute__((ext_vector_type(8))) short bfrag;   // 8 bf16 = 4 VGPRs
typedef __attribute__((ext_vector_type(4))) float ffrag;   // mfma accumulator

__device__ __forceinline__ uint16_t f2bf(float f) {
  uint32_t u = __float_as_uint(f);
  u += 0x7fff + ((u >> 16) & 1);   // round-to-nearest-even
  return (uint16_t)(u >> 16);
}
__device__ __forceinline__ uint32_t pack2(float a, float b) {
  return (uint32_t)f2bf(a) | ((uint32_t)f2bf(b) << 16);
}

// ---------- x (fp32) -> h (bf16, packed pairs) ----------
__global__ void k_cast_x(const float* __restrict__ x, uint32_t* __restrict__ h) {
  int n = NN * 64;
  for (int i = blockIdx.x * blockDim.x + threadIdx.x; i < n; i += gridDim.x * blockDim.x) {
    float2 v = ((const float2*)x)[i];
    h[i] = pack2(v.x, v.y);
  }
}

// ---------- Wc[l][r] = Wg[l][r] @ Wfc[l]  (fp32, folds both matmuls into one) ----------
__global__ void k_matmul_wc(const float* __restrict__ Wg0, const float* __restrict__ Wg1,
                            const float* __restrict__ Wfc, float* __restrict__ Wc) {
  int b = blockIdx.x;                 // 24 blocks: m*4 + kq
  int m = b >> 2, kq = b & 3;
  int l = m / 3, rel = m % 3;
  int t = threadIdx.x;
  int n = t & 127, kh = t >> 7;
  int k0 = kq * 32 + kh * 16;
  const float* Wg = (l ? Wg1 : Wg0) + rel * 16384;
  const float* Wf = Wfc + (size_t)l * 16384;
  for (int k = k0; k < k0 + 16; k++) {
    float acc = 0.f;
    for (int kk = 0; kk < 128; kk++) acc = fmaf(Wg[k * 128 + kk], Wf[kk * 128 + n], acc);
    Wc[(size_t)m * 16384 + k * 128 + n] = acc;
  }
}

// ---------- pre-swizzle the 6 Wc matrices into MFMA B-fragment order ----------
// wswz[m][f=t*8+ct][lane][j] = Wc[m][t*32 + (lane>>4)*8 + j][ct*16 + (lane&15)]
__global__ void k_prep_w(const float* __restrict__ Wc, uint16_t* __restrict__ wswz) {
  int idx = blockIdx.x * 256 + threadIdx.x;          // 0 .. 98303 (6 * 16384)
  int rem = idx & 16383;
  int m = idx >> 14;
  int j = rem & 7;
  int lane = (rem >> 3) & 63;
  int f = rem >> 9;                                   // t*8+ct
  int t = f >> 3, ct = f & 7;
  int k = t * 32 + (lane >> 4) * 8 + j;
  int n = ct * 16 + (lane & 15);
  wswz[idx] = f2bf(Wc[(size_t)m * 16384 + k * 128 + n]);
}

// ---------- tiny constants: bias2 = (sum_r bg)@Wfc + bfc ; BN folded to g2,b2 ----------
__global__ void k_prep_consts(const float* __restrict__ bg0, const float* __restrict__ bg1,
                              const float* __restrict__ Wfc, const float* __restrict__ bfc,
                              const float* __restrict__ gamma, const float* __restrict__ beta,
                              const float* __restrict__ mean, const float* __restrict__ var,
                              float* __restrict__ cst) {
  int tid = threadIdx.x;              // 0..255 = l*128 + n
  int l = tid >> 7, n = tid & 127;
  const float* bg = l ? bg1 : bg0;
  float acc = bfc[l * 128 + n];
  for (int k = 0; k < 128; k++) {
    float bsum = bg[k] + bg[128 + k] + bg[256 + k];
    acc += bsum * Wfc[l * 16384 + k * 128 + n];
  }
  cst[tid] = acc;                                    // bias2
  float g = gamma[tid] * rsqrtf(var[tid] + 1e-5f);
  cst[256 + tid] = g;                                // g2
  cst[512 + tid] = beta[tid] - mean[tid] * g;        // b2
}

// ---------- build 1: per-slice LDS bucket histograms, tiny global merge ----------
__global__ void k_bhist(const int* __restrict__ s0, const int* __restrict__ s1,
                        const int* __restrict__ s2, const int* __restrict__ d0,
                        const int* __restrict__ d1, const int* __restrict__ d2,
                        uint32_t* __restrict__ bh) {
  int r = blockIdx.y, blk = blockIdx.x, t = threadIdx.x;
  __shared__ uint32_t hD[NBK], hS[NBK];
  for (int i = t; i < NBK; i += 256) { hD[i] = 0; hS[i] = 0; }
  __syncthreads();
  const int4* sp = (const int4*)((r == 0) ? s0 : (r == 1) ? s1 : s2);
  const int4* dp = (const int4*)((r == 0) ? d0 : (r == 1) ? d1 : d2);
  int base = blk * (NE4 / NSL);
  for (int i = t; i < NE4 / NSL; i += 256) {
    int4 s = sp[base + i];
    int4 d = dp[base + i];
    atomicAdd(&hD[d.x >> 9], 1u); atomicAdd(&hD[d.y >> 9], 1u);
    atomicAdd(&hD[d.z >> 9], 1u); atomicAdd(&hD[d.w >> 9], 1u);
    atomicAdd(&hS[s.x >> 9], 1u); atomicAdd(&hS[s.y >> 9], 1u);
    atomicAdd(&hS[s.z >> 9], 1u); atomicAdd(&hS[s.w >> 9], 1u);
  }
  __syncthreads();
  for (int i = t; i < NBK; i += 256) {
    if (hD[i]) atomicAdd(&bh[r * NBK + i], hD[i]);
    if (hS[i]) atomicAdd(&bh[(3 + r) * NBK + i], hS[i]);
  }
}

// ---------- build 2: exclusive scan of each segment's 196 bucket counts ----------
__global__ void k_bscan(const uint32_t* __restrict__ bh, int* __restrict__ bases,
                        uint32_t* __restrict__ cur, int* __restrict__ rowptr) {
  int seg = blockIdx.x, t = threadIdx.x;     // 256 threads
  int lane = t & 63, wid = t >> 6;
  int v = (t < NBK) ? (int)bh[seg * NBK + t] : 0;
  int x = v;
#pragma unroll
  for (int o = 1; o < 64; o <<= 1) { int y = __shfl_up(x, o); if (lane >= o) x += y; }
  __shared__ int ws[4];
  if (lane == 63) ws[wid] = x;
  __syncthreads();
  int woff = 0;
  for (int i = 0; i < wid; i++) woff += ws[i];
  int incl = woff + x, excl = incl - v;
  if (t < NBK) { bases[seg * (NBK + 1) + t] = excl; cur[seg * NBK + t] = (uint32_t)excl; }
  if (t == 255) bases[seg * (NBK + 1) + NBK] = incl;   // = NE
  if (seg < 3 && t == 0) rowptr[seg * NNP1 + NN] = NE;
}

// ---------- build 3: scatter edges into buckets (block-chunk claims, LDS cursors) ----------
__global__ void k_bscatter(const int* __restrict__ s0, const int* __restrict__ s1,
                           const int* __restrict__ s2, const int* __restrict__ d0,
                           const int* __restrict__ d1, const int* __restrict__ d2,
                           uint32_t* __restrict__ cur, uint32_t* __restrict__ pairs,
                           uint16_t* __restrict__ srcs) {
  int r = blockIdx.y, blk = blockIdx.x, t = threadIdx.x;
  __shared__ uint32_t hD[NBK], hS[NBK];
  for (int i = t; i < NBK; i += 256) { hD[i] = 0; hS[i] = 0; }
  __syncthreads();
  const int4* sp = (const int4*)((r == 0) ? s0 : (r == 1) ? s1 : s2);
  const int4* dp = (const int4*)((r == 0) ? d0 : (r == 1) ? d1 : d2);
  int base = blk * (NE4 / NSL);
  for (int i = t; i < NE4 / NSL; i += 256) {
    int4 s = sp[base + i];
    int4 d = dp[base + i];
    atomicAdd(&hD[d.x >> 9], 1u); atomicAdd(&hD[d.y >> 9], 1u);
    atomicAdd(&hD[d.z >> 9], 1u); atomicAdd(&hD[d.w >> 9], 1u);
    atomicAdd(&hS[s.x >> 9], 1u); atomicAdd(&hS[s.y >> 9], 1u);
    atomicAdd(&hS[s.z >> 9], 1u); atomicAdd(&hS[s.w >> 9], 1u);
  }
  __syncthreads();
  for (int i = t; i < NBK; i += 256) {
    hD[i] = atomicAdd(&cur[r * NBK + i], hD[i]);
    hS[i] = atomicAdd(&cur[(3 + r) * NBK + i], hS[i]);
  }
  __syncthreads();
  uint32_t* pr = pairs + (size_t)r * NE;
  uint16_t* sr = srcs + (size_t)r * NE;
#define SCAT1(S, D) { \
    uint32_t p = atomicAdd(&hD[(D) >> 9], 1u); \
    pr[p] = (uint32_t)(((D) & 511) << 17) | (uint32_t)(S); \
    uint32_t q = atomicAdd(&hS[(S) >> 9], 1u); \
    sr[q] = (uint16_t)((S) & 511); }
  for (int i = t; i < NE4 / NSL; i += 256) {
    int4 s = sp[base + i];
    int4 d = dp[base + i];
    SCAT1(s.x, d.x) SCAT1(s.y, d.y) SCAT1(s.z, d.z) SCAT1(s.w, d.w)
  }
#undef SCAT1
}

// ---------- build 4: per-bucket CSR (rowptr, s_in, col) ----------
__global__ void k_bucket_csr(const uint32_t* __restrict__ pairs, const int* __restrict__ bases,
                             int* __restrict__ rowptr, float* __restrict__ s_in,
                             int* __restrict__ col) {
  int b = blockIdx.x, r = blockIdx.y, t = threadIdx.x;
  int node0 = b << 9;
  int nc = min(512, NN - node0);
  int rb = bases[r * (NBK + 1) + b];
  int m = bases[r * (NBK + 1) + b + 1] - rb;
  __shared__ int cnt[512];
  __shared__ int exc[512];
  __shared__ int ws[4];
  cnt[t] = 0; cnt[t + 256] = 0;
  __syncthreads();
  const uint32_t* pp = pairs + (size_t)r * NE + rb;
  for (int i = t; i < m; i += 256) atomicAdd(&cnt[pp[i] >> 17], 1);
  __syncthreads();
  int v0 = cnt[2 * t], v1 = cnt[2 * t + 1];
  int s = v0 + v1, x = s;
  int lane = t & 63, wid = t >> 6;
#pragma unroll
  for (int o = 1; o < 64; o <<= 1) { int y = __shfl_up(x, o); if (lane >= o) x += y; }
  if (lane == 63) ws[wid] = x;
  __syncthreads();
  int woff = 0;
  for (int i = 0; i < wid; i++) woff += ws[i];
  int e0 = woff + x - s;
  exc[2 * t] = e0;
  exc[2 * t + 1] = e0 + v0;
  __syncthreads();
  for (int i = t; i < nc; i += 256) {
    rowptr[r * NNP1 + node0 + i] = rb + exc[i];
    s_in[r * NN + node0 + i] = rsqrtf((float)(cnt[i] < 1 ? 1 : cnt[i]));
  }
  __syncthreads();
  int* cl = col + (size_t)r * NE + rb;
  for (int i = t; i < m; i += 256) {
    uint32_t e = pp[i];
    int p = atomicAdd(&exc[e >> 17], 1);
    cl[p] = (int)(e & 0x1FFFF);
  }
}

// ---------- build 5: per-bucket out-degree -> s_out ----------
__global__ void k_bucket_sout(const uint16_t* __restrict__ srcs, const int* __restrict__ bases,
                              float* __restrict__ s_out) {
  int b = blockIdx.x, r = blockIdx.y, t = threadIdx.x;
  int node0 = b << 9;
  int nc = min(512, NN - node0);
  int rb = bases[(3 + r) * (NBK + 1) + b];
  int m = bases[(3 + r) * (NBK + 1) + b + 1] - rb;
  __shared__ int cnt[512];
  cnt[t] = 0; cnt[t + 256] = 0;
  __syncthreads();
  const uint16_t* pp = srcs + (size_t)r * NE + rb;
  for (int i = t; i < m; i += 256) atomicAdd(&cnt[pp[i]], 1);
  __syncthreads();
  for (int i = t; i < nc; i += 256)
    s_out[r * NN + node0 + i] = rsqrtf((float)(cnt[i] < 1 ? 1 : cnt[i]));
}

// ---------- FUSED aggregate + FC: block = 16 dst nodes, all 3 relations ----------
// phase 1: gather 48 rows (rel,node) into LDS A[16][APAD] (bf16 pairs, R4 readlane scheme)
// phase 2: out[16,128] = relu([A0|A1|A2] @ [Wc0;Wc1;Wc2] + bias2), BN folded.
//          wave wid computes cols [wid*32, wid*32+32).
__global__ __launch_bounds__(256) void k_agg_fc(const uint32_t* __restrict__ h,
                                                const int* __restrict__ rowptr,
                                                const int* __restrict__ col,
                                                const float* __restrict__ s_out,
                                                const float* __restrict__ s_in,
                                                const short* __restrict__ wswz,
                                                const float* __restrict__ cst, int l,
                                                uint16_t* __restrict__ hout,
                                                float* __restrict__ fout, int wf32) {
  __shared__ uint32_t A[16 * APAD];
  int base = blockIdx.x * 16;
  int tid = threadIdx.x;
  int wid = tid >> 6, lane = tid & 63;
  // ---- phase 1: 12 (rel,node) tasks per wave ----
  for (int t = wid * 12; t < wid * 12 + 12; t++) {
    int rel = t >> 4, ni = t & 15;
    int node = base + ni;
    const int* rp = rowptr + rel * NNP1;
    int beg = rp[node], end = rp[node + 1];
    const int* cl = col + (size_t)rel * NE;
    const float* so = s_out + rel * NN;
    float a0 = 0.f, a1 = 0.f;
    for (int bs = beg; bs < end; bs += 64) {
      int idx = bs + lane;
      int sv = 0, wb = 0;
      if (idx < end) { sv = cl[idx]; wb = __float_as_int(so[sv]); }
      int cnt = min(64, end - bs);
      int cnt8 = (cnt + 7) & ~7;   // tail lanes hold s=0,w=0 -> harmless row-0 gathers
      for (int j = 0; j < cnt8; j += 8) {
        uint32_t hv[8]; float ww[8];
#pragma unroll
        for (int u = 0; u < 8; u++) {
          int ss = __builtin_amdgcn_readlane(sv, j + u);
          ww[u] = __int_as_float(__builtin_amdgcn_readlane(wb, j + u));
          hv[u] = h[(size_t)ss * 64 + lane];
        }
#pragma unroll
        for (int u = 0; u < 8; u++) {
          a0 = fmaf(__uint_as_float(hv[u] << 16), ww[u], a0);
          a1 = fmaf(__uint_as_float(hv[u] & 0xffff0000u), ww[u], a1);
        }
      }
    }
    float sc = s_in[rel * NN + node];
    A[ni * APAD + rel * 64 + lane] = pack2(a0 * sc, a1 * sc);
  }
  __syncthreads();
  // ---- phase 2: K=384 MFMA from LDS A + global B frags ----
  int q = lane >> 4, n0 = lane & 15;
  ffrag acc[2] = {(ffrag){0.f,0.f,0.f,0.f}, (ffrag){0.f,0.f,0.f,0.f}};
  const bfrag* wb2 = (const bfrag*)(wswz + (size_t)(l * 3) * 16384);
  for (int kt = 0; kt < 12; kt++) {
    int rel = kt >> 2, kt4 = kt & 3;
    bfrag a = *(const bfrag*)(&A[n0 * APAD + rel * 64 + kt4 * 16 + q * 4]);
    const bfrag* wk = wb2 + (size_t)rel * 2048 + (size_t)(kt4 * 8) * 64 + lane;
#pragma unroll
    for (int c = 0; c < 2; c++) {
      bfrag B = wk[(size_t)(wid * 2 + c) * 64];
      acc[c] = __builtin_amdgcn_mfma_f32_16x16x32_bf16(a, B, acc[c], 0, 0, 0);
    }
  }
#pragma unroll
  for (int c = 0; c < 2; c++) {
    int ct = wid * 2 + c;
    int colid = ct * 16 + n0;
    float bb = cst[l * 128 + colid];
    float gg = cst[256 + l * 128 + colid];
    float b2 = cst[512 + l * 128 + colid];
#pragma unroll
    for (int i = 0; i < 4; i++) {
      int row = base + q * 4 + i;
      float y = acc[c][i] + bb;
      y = fmaxf(y, 0.f);
      float hv = fmaf(y, gg, b2);
      size_t oi = (size_t)row * 128 + colid;
      if (wf32) fout[oi] = hv;
      else hout[oi] = f2bf(hv);
    }
  }
}

extern "C" void kernel_launch(void* const* d_in, const int* in_sizes, int n_in,
                              void* d_out, int out_size, void* d_ws, size_t ws_size,
                              hipStream_t stream) {
  const float* x = (const float*)d_in[0];
  const int* s0 = (const int*)d_in[1]; const int* d0 = (const int*)d_in[2];
  const int* s1 = (const int*)d_in[3]; const int* d1 = (const int*)d_in[4];
  const int* s2 = (const int*)d_in[5]; const int* d2 = (const int*)d_in[6];
  const float* Wg0 = (const float*)d_in[7];
  const float* bg0 = (const float*)d_in[8];
  const float* Wg1 = (const float*)d_in[9];
  const float* bg1 = (const float*)d_in[10];
  const float* Wfc = (const float*)d_in[11];
  const float* bfc = (const float*)d_in[12];
  const float* gamma = (const float*)d_in[13];
  const float* beta = (const float*)d_in[14];
  const float* mean = (const float*)d_in[15];
  const float* var = (const float*)d_in[16];

  char* ws = (char*)d_ws;
  size_t off = 0;
  auto alloc = [&](size_t bytes) { size_t o = off; off = (off + bytes + 255) & ~(size_t)255; return o; };
  size_t o_bh    = alloc((size_t)6 * NBK * 4);
  size_t o_bases = alloc((size_t)6 * (NBK + 1) * 4);
  size_t o_cur   = alloc((size_t)6 * NBK * 4);
  size_t o_sin   = alloc((size_t)3 * NN * 4);
  size_t o_sout  = alloc((size_t)3 * NN * 4);
  size_t o_rp    = alloc((size_t)3 * NNP1 * 4);
  size_t o_col   = alloc((size_t)3 * NE * 4);
  size_t o_wc    = alloc((size_t)6 * 16384 * 4);
  size_t o_wswz  = alloc((size_t)6 * 16384 * 2);
  size_t o_cst   = alloc((size_t)768 * 4);
  size_t o_h     = alloc((size_t)NN * 128 * 2);
  size_t o_h2    = alloc((size_t)NN * 128 * 2);
  size_t o_pairs = alloc((size_t)3 * NE * 4);
  size_t o_srcs  = alloc((size_t)3 * NE * 2);
  (void)ws_size; (void)in_sizes; (void)n_in; (void)out_size;

  uint32_t* bh   = (uint32_t*)(ws + o_bh);
  int* bases     = (int*)(ws + o_bases);
  uint32_t* cur  = (uint32_t*)(ws + o_cur);
  float* s_in    = (float*)(ws + o_sin);
  float* s_out   = (float*)(ws + o_sout);
  int* rowptr    = (int*)(ws + o_rp);
  int* col       = (int*)(ws + o_col);
  float* Wc      = (float*)(ws + o_wc);
  uint16_t* wswz = (uint16_t*)(ws + o_wswz);
  float* cst     = (float*)(ws + o_cst);
  uint32_t* h    = (uint32_t*)(ws + o_h);
  uint32_t* h2   = (uint32_t*)(ws + o_h2);
  uint32_t* pairs = (uint32_t*)(ws + o_pairs);
  uint16_t* srcs  = (uint16_t*)(ws + o_srcs);

  hipMemsetAsync(ws + o_bh, 0, (size_t)6 * NBK * 4, stream);

  k_cast_x<<<2048, 256, 0, stream>>>(x, h);
  k_matmul_wc<<<24, 256, 0, stream>>>(Wg0, Wg1, Wfc, Wc);
  k_prep_w<<<384, 256, 0, stream>>>(Wc, wswz);
  k_prep_consts<<<1, 256, 0, stream>>>(bg0, bg1, Wfc, bfc, gamma, beta, mean, var, cst);
  k_bhist<<<dim3(NSL, 3), 256, 0, stream>>>(s0, s1, s2, d0, d1, d2, bh);
  k_bscan<<<6, 256, 0, stream>>>(bh, bases, cur, rowptr);
  k_bscatter<<<dim3(NSL, 3), 256, 0, stream>>>(s0, s1, s2, d0, d1, d2, cur, pairs, srcs);
  k_bucket_csr<<<dim3(NBK, 3), 256, 0, stream>>>(pairs, bases, rowptr, s_in, col);
  k_bucket_sout<<<dim3(NBK, 3), 256, 0, stream>>>(srcs, bases, s_out);

  // layer 0: h -> h2 (bf16);  layer 1: h2 -> d_out (fp32)
  k_agg_fc<<<6250, 256, 0, stream>>>(h, rowptr, col, s_out, s_in,
                                     (const short*)wswz, cst, 0,
                                     (uint16_t*)h2, (float*)d_out, 0);
  k_agg_fc<<<6250, 256, 0, stream>>>(h2, rowptr, col, s_out, s_in,
                                     (const short*)wswz, cst, 1,
                                     (uint16_t*)h2, (float*)d_out, 1);
}